// Round 12
// baseline (298.387 us; speedup 1.0000x reference)
//
#include <hip/hip_runtime.h>
#include <hip/hip_fp16.h>
#include <math.h>

constexpr int F = 128;
constexpr int C = 40;
constexpr int LDH = 136;   // padded LDS stride in halves
constexpr int BSHIFT = 8;  // 256 dst per coarse bucket
constexpr int BSIZE = 1 << BSHIFT;
constexpr int CHUNK = 4096;  // edges per histogram/scatter block (391 blocks)

typedef __attribute__((ext_vector_type(8))) _Float16 half8;
typedef __attribute__((ext_vector_type(4))) float float4v;
typedef __attribute__((ext_vector_type(2))) float floatx2;

// ---------------- fused prep: conv fp32->fp8 + weight transpose + coarse hist ----------------
// blocks [0,BA): coarse histogram; [BA,BA+4): weight transpose (16KB staging, 4 passes) —
// the w4 block also zeroes fp8 row N (dummy row for agg address-masking);
// rest: x fp32 -> fp8 e4m3 row-major (the ONLY feature table — self term also decoded fp8).
// coarse_count+pos0 pre-zeroed by hipMemsetAsync.

__global__ __launch_bounds__(256) void fused_prep_kernel(
        const float* __restrict__ x, unsigned char* __restrict__ xq, int n4,
        const int* __restrict__ dst, int E, int NB, int* __restrict__ coarse_count,
        const float* __restrict__ w1, const float* __restrict__ w2,
        const float* __restrict__ w3, const float* __restrict__ w4,
        __half* __restrict__ w1t, __half* __restrict__ w2t,
        __half* __restrict__ w3t, __half* __restrict__ w4t, int BA, int N) {
    __shared__ float smem[4096];  // 16KB, shared by all roles
    int b = blockIdx.x, t = threadIdx.x;
    if (b < BA) {
        int* hist = (int*)smem;
        int c0 = b * CHUNK, cend = min(c0 + CHUNK, E);
        for (int i = t; i < NB; i += 256) hist[i] = 0;
        __syncthreads();
        for (int i = c0 + t; i < cend; i += 256)
            atomicAdd(&hist[dst[i] >> BSHIFT], 1);
        __syncthreads();
        for (int i = t; i < NB; i += 256)
            if (hist[i]) atomicAdd(&coarse_count[i], hist[i]);
        return;
    }
    if (b < BA + 4) {
        const float* in; __half* outp; int Nin, Npad;
        switch (b - BA) {
            case 0:  in = w1; outp = w1t; Nin = 128; Npad = 128; break;
            case 1:  in = w2; outp = w2t; Nin = 128; Npad = 128; break;
            case 2:  in = w3; outp = w3t; Nin = 128; Npad = 128; break;
            default: in = w4; outp = w4t; Nin = 40;  Npad = 48;  break;
        }
        for (int p = 0; p < 4; ++p) {  // k rows [32p, 32p+32)
            int nf4 = 32 * Nin / 4;
            const float4* srcv = (const float4*)(in + 32 * p * Nin);
            for (int i = t; i < nf4; i += 256) ((float4*)smem)[i] = srcv[i];
            __syncthreads();
            int total = Npad * 16;
            for (int i = t; i < total; i += 256) {
                int n = i >> 4, wl = i & 15;
                float lo = 0.f, hi = 0.f;
                if (n < Nin) {
                    lo = smem[(2 * wl) * Nin + n];
                    hi = smem[(2 * wl + 1) * Nin + n];
                }
                __half2 h = __floats2half2_rn(lo, hi);
                ((unsigned*)outp)[n * 64 + 16 * p + wl] = __builtin_bit_cast(unsigned, h);
            }
            __syncthreads();
        }
        if (b - BA == 3 && t < 8)  // zero dummy row fq[N] (survives mlp1: it writes rows < N)
            *(((uint4*)(xq + (size_t)N * F)) + t) = make_uint4(0u, 0u, 0u, 0u);
        return;
    }
    int i = (b - BA - 4) * 256 + t;
    if (i >= n4) return;
    float4 v = ((const float4*)x)[i];
    unsigned p8 = __builtin_amdgcn_cvt_pk_fp8_f32(v.x, v.y, 0u, false);
    p8 = __builtin_amdgcn_cvt_pk_fp8_f32(v.z, v.w, p8, true);
    ((unsigned*)xq)[i] = p8;
}

// ---------------- CSR build: scan-fused scatter + per-bucket sort (r9-proven) ----------------
// Both kernels redundantly compute the <=512-entry exclusive scan of coarse_count in LDS
// (deterministic); scatter allocates cursors via memset-zeroed pos0[].

__global__ __launch_bounds__(512) void bucket_scatter_kernel(
        const int* __restrict__ src, const int* __restrict__ dst, int E, int NB,
        const int* __restrict__ coarse_count, int* __restrict__ pos0,
        unsigned* __restrict__ pairs) {
    __shared__ int scn[512];
    __shared__ int hist[512];
    __shared__ int base[512];
    int t = threadIdx.x;
    int v = (t < NB) ? coarse_count[t] : 0;
    scn[t] = v;
    __syncthreads();
    for (int d = 1; d < 512; d <<= 1) {
        int add = (t >= d) ? scn[t - d] : 0;
        __syncthreads();
        scn[t] += add;
        __syncthreads();
    }
    int cstart = scn[t] - v;  // exclusive prefix for bucket t
    hist[t] = 0;
    __syncthreads();
    int c0 = blockIdx.x * CHUNK, cend = min(c0 + CHUNK, E);
    for (int i = c0 + t; i < cend; i += 512)
        atomicAdd(&hist[dst[i] >> BSHIFT], 1);
    __syncthreads();
    int h = hist[t];
    base[t] = (h > 0) ? (cstart + atomicAdd(&pos0[t], h)) : 0;
    hist[t] = 0;  // reuse as local offset
    __syncthreads();
    for (int i = c0 + t; i < cend; i += 512) {
        int d = dst[i];
        int b = d >> BSHIFT;
        int p = base[b] + atomicAdd(&hist[b], 1);
        pairs[p] = ((unsigned)(d & (BSIZE - 1)) << 24) | (unsigned)src[i];
    }
}

// one block per bucket; redundant coarse scan -> fine hist + scan -> row_start + PRE-SHIFTED
// byte-offset scatter (src*128). Last block pads src_sorted[E..E+31] with the dummy offset.
__global__ __launch_bounds__(512) void bucket_sort_kernel(const unsigned* __restrict__ pairs,
                                                          const int* __restrict__ coarse_count,
                                                          int NB, int N, int E,
                                                          int* __restrict__ row_start,
                                                          unsigned* __restrict__ src_sorted) {
    __shared__ int scn[512];
    __shared__ int hist[256];
    __shared__ int tmp[256];
    int b = blockIdx.x, t = threadIdx.x;
    int v = (t < NB) ? coarse_count[t] : 0;
    scn[t] = v;
    __syncthreads();
    for (int d = 1; d < 512; d <<= 1) {
        int add = (t >= d) ? scn[t - d] : 0;
        __syncthreads();
        scn[t] += add;
        __syncthreads();
    }
    int end = scn[b];
    int start = end - coarse_count[b];
    int base = b << BSHIFT;
    if (t < 256) hist[t] = 0;
    __syncthreads();
    for (int i = start + t; i < end; i += 512)
        atomicAdd(&hist[pairs[i] >> 24], 1);
    __syncthreads();
    int hv = (t < 256) ? hist[t] : 0;
    if (t < 256) tmp[t] = hv;
    __syncthreads();
    for (int d = 1; d < 256; d <<= 1) {
        int add = (t >= d && t < 256) ? tmp[t - d] : 0;
        __syncthreads();
        if (t < 256) tmp[t] += add;
        __syncthreads();
    }
    if (t < 256) {
        int ex = start + tmp[t] - hv;
        if (base + t < N) row_start[base + t] = ex;
        hist[t] = ex;
    }
    __syncthreads();
    for (int i = start + t; i < end; i += 512) {
        unsigned u = pairs[i];
        int p = atomicAdd(&hist[u >> 24], 1);
        src_sorted[p] = (u & 0x00FFFFFFu) << 7;   // byte offset (row stride 128)
    }
    if (b == NB - 1 && t < 32) src_sorted[E + t] = ((unsigned)N) << 7;
    if (b == 0 && t == 0) row_start[N] = E;
}

// ---------------- aggregation: fp8 gather + fp8 self, byte-offset CSR, dummy-row masking ----
// r1/r6-proven structure: one wave per node, 16-edge batches, 4 independent row gathers in
// flight (uint2/lane fp8 rows). src_sorted holds PRE-SHIFTED byte offsets (padded past E);
// invalid slots redirect to the zero row fq[N]. Decode via v_cvt_pk_f32_fp8, packed-f32
// accumulate; self term ALSO decoded from the fp8 table (no fp16 copy exists).

__global__ __launch_bounds__(256) void agg_f16_kernel(const unsigned char* __restrict__ featq,
        const int* __restrict__ row_start, const unsigned* __restrict__ src_sorted,
        const float* __restrict__ eps_ptr, __half* __restrict__ out, int N) {
    int wid = (int)((blockIdx.x * blockDim.x + threadIdx.x) >> 6);
    int lane = threadIdx.x & 63;
    if (wid >= N) return;
    int q = lane >> 4, l16 = lane & 15;
    int s = row_start[wid], e = row_start[wid + 1];
    const unsigned dummy = ((unsigned)N) << 7;
    const unsigned char* fb = featq + l16 * 8;  // per-lane base (folds the l16*8)
    uint2 su = *((const uint2*)(fb + ((size_t)(unsigned)wid << 7)));  // self (issued early)
    float ep1 = 1.0f + *eps_ptr;
    floatx2 accA[4], accB[4];
#pragma unroll
    for (int j = 0; j < 4; ++j) {
        accA[j] = (floatx2){0.f, 0.f};
        accB[j] = (floatx2){0.f, 0.f};
    }
    for (int i0 = s; i0 < e; i0 += 16) {
        unsigned off = src_sorted[i0 + l16];  // padded region makes this always safe
        unsigned o0 = (unsigned)__shfl((int)off, q);
        unsigned o1 = (unsigned)__shfl((int)off, q + 4);
        unsigned o2 = (unsigned)__shfl((int)off, q + 8);
        unsigned o3 = (unsigned)__shfl((int)off, q + 12);
        o0 = (i0 + q < e) ? o0 : dummy;
        o1 = (i0 + q + 4 < e) ? o1 : dummy;
        o2 = (i0 + q + 8 < e) ? o2 : dummy;
        o3 = (i0 + q + 12 < e) ? o3 : dummy;
        uint2 u0 = *((const uint2*)(fb + o0));
        uint2 u1 = *((const uint2*)(fb + o1));
        uint2 u2 = *((const uint2*)(fb + o2));
        uint2 u3 = *((const uint2*)(fb + o3));
        accA[0] += __builtin_amdgcn_cvt_pk_f32_fp8(u0.x, false);
        accA[1] += __builtin_amdgcn_cvt_pk_f32_fp8(u0.x, true);
        accA[2] += __builtin_amdgcn_cvt_pk_f32_fp8(u0.y, false);
        accA[3] += __builtin_amdgcn_cvt_pk_f32_fp8(u0.y, true);
        accB[0] += __builtin_amdgcn_cvt_pk_f32_fp8(u1.x, false);
        accB[1] += __builtin_amdgcn_cvt_pk_f32_fp8(u1.x, true);
        accB[2] += __builtin_amdgcn_cvt_pk_f32_fp8(u1.y, false);
        accB[3] += __builtin_amdgcn_cvt_pk_f32_fp8(u1.y, true);
        accA[0] += __builtin_amdgcn_cvt_pk_f32_fp8(u2.x, false);
        accA[1] += __builtin_amdgcn_cvt_pk_f32_fp8(u2.x, true);
        accA[2] += __builtin_amdgcn_cvt_pk_f32_fp8(u2.y, false);
        accA[3] += __builtin_amdgcn_cvt_pk_f32_fp8(u2.y, true);
        accB[0] += __builtin_amdgcn_cvt_pk_f32_fp8(u3.x, false);
        accB[1] += __builtin_amdgcn_cvt_pk_f32_fp8(u3.x, true);
        accB[2] += __builtin_amdgcn_cvt_pk_f32_fp8(u3.y, false);
        accB[3] += __builtin_amdgcn_cvt_pk_f32_fp8(u3.y, true);
    }
    float a[8];
#pragma unroll
    for (int j = 0; j < 4; ++j) {
        floatx2 m = accA[j] + accB[j];
        a[2 * j] = m.x;
        a[2 * j + 1] = m.y;
    }
#pragma unroll
    for (int j = 0; j < 8; ++j) {
        a[j] += __shfl_xor(a[j], 16);
        a[j] += __shfl_xor(a[j], 32);
    }
    if (q == 0) {
        floatx2 s01 = __builtin_amdgcn_cvt_pk_f32_fp8(su.x, false);
        floatx2 s23 = __builtin_amdgcn_cvt_pk_f32_fp8(su.x, true);
        floatx2 s45 = __builtin_amdgcn_cvt_pk_f32_fp8(su.y, false);
        floatx2 s67 = __builtin_amdgcn_cvt_pk_f32_fp8(su.y, true);
        a[0] = fmaf(ep1, s01.x, a[0]); a[1] = fmaf(ep1, s01.y, a[1]);
        a[2] = fmaf(ep1, s23.x, a[2]); a[3] = fmaf(ep1, s23.y, a[3]);
        a[4] = fmaf(ep1, s45.x, a[4]); a[5] = fmaf(ep1, s45.y, a[5]);
        a[6] = fmaf(ep1, s67.x, a[6]); a[7] = fmaf(ep1, s67.y, a[7]);
        uint4 ou;
        ou.x = __builtin_bit_cast(unsigned, __floats2half2_rn(a[0], a[1]));
        ou.y = __builtin_bit_cast(unsigned, __floats2half2_rn(a[2], a[3]));
        ou.z = __builtin_bit_cast(unsigned, __floats2half2_rn(a[4], a[5]));
        ou.w = __builtin_bit_cast(unsigned, __floats2half2_rn(a[6], a[7]));
        *(((uint4*)(out + (size_t)wid * F)) + l16) = ou;
    }
}

// ---------------- mlp1 (MFMA): fq = fp8(relu(relu(A@w1+b1)@w2+b2)) ----------------
// Weights read DIRECTLY from global (32KB tables, L1/L2-resident broadcast — r4-proven
// pattern). LDS = ldsA + ldsB only (18.4 KB) -> 8 blocks/CU, full 32-wave occupancy;
// two weight-staging barrier pairs removed.

__global__ __launch_bounds__(256) void mlp1_mfma_kernel(const __half* __restrict__ A,
        const __half* __restrict__ w1t, const float* __restrict__ b1,
        const __half* __restrict__ w2t, const float* __restrict__ b2,
        unsigned char* __restrict__ outq, int N) {
    __shared__ __half ldsA[64 * LDH];
    __shared__ float ldsB[256];
    int t = threadIdx.x;
    int wave = t >> 6, lane = t & 63, quad = lane >> 4, l16 = lane & 15;
    int br = blockIdx.x * 64;
    if (t < 128) ldsB[t] = b1[t];
    else         ldsB[t] = b2[t - 128];
    for (int i = t; i < 1024; i += 256) {
        int r = i >> 4, c = i & 15;
        int gr = br + r;
        uint4 v = make_uint4(0u, 0u, 0u, 0u);
        if (gr < N) v = *((const uint4*)(A + (size_t)gr * F + c * 8));
        *((uint4*)&ldsA[r * LDH + c * 8]) = v;
    }
    __syncthreads();

    int ct0 = wave * 2;
    float4v acc[4][2];
    float4v zero = {0.f, 0.f, 0.f, 0.f};
#pragma unroll
    for (int i = 0; i < 4; ++i)
#pragma unroll
        for (int j = 0; j < 2; ++j) acc[i][j] = zero;

#pragma unroll
    for (int ks = 0; ks < 4; ++ks) {
        half8 af[4], wf[2];
#pragma unroll
        for (int i = 0; i < 4; ++i)
            af[i] = *((const half8*)&ldsA[(i * 16 + l16) * LDH + ks * 32 + quad * 8]);
#pragma unroll
        for (int j = 0; j < 2; ++j)
            wf[j] = *((const half8*)(w1t + ((ct0 + j) * 16 + l16) * 128 + ks * 32 + quad * 8));
#pragma unroll
        for (int i = 0; i < 4; ++i)
#pragma unroll
            for (int j = 0; j < 2; ++j)
                acc[i][j] = __builtin_amdgcn_mfma_f32_16x16x32_f16(wf[j], af[i], acc[i][j], 0, 0, 0);
    }
    __syncthreads();
#pragma unroll
    for (int j = 0; j < 2; ++j) {
        int c = ct0 + j;
        float4 bb = *((const float4*)&ldsB[c * 16 + quad * 4]);
#pragma unroll
        for (int i = 0; i < 4; ++i) {
            float v0 = acc[i][j][0] + bb.x; v0 = v0 > 0.f ? v0 : 0.f;
            float v1 = acc[i][j][1] + bb.y; v1 = v1 > 0.f ? v1 : 0.f;
            float v2 = acc[i][j][2] + bb.z; v2 = v2 > 0.f ? v2 : 0.f;
            float v3 = acc[i][j][3] + bb.w; v3 = v3 > 0.f ? v3 : 0.f;
            __half2 h0 = __floats2half2_rn(v0, v1);
            __half2 h1 = __floats2half2_rn(v2, v3);
            uint2 o;
            o.x = __builtin_bit_cast(unsigned, h0);
            o.y = __builtin_bit_cast(unsigned, h1);
            *((uint2*)&ldsA[(i * 16 + l16) * LDH + c * 16 + quad * 4]) = o;
        }
    }
    __syncthreads();

#pragma unroll
    for (int i = 0; i < 4; ++i)
#pragma unroll
        for (int j = 0; j < 2; ++j) acc[i][j] = zero;
#pragma unroll
    for (int ks = 0; ks < 4; ++ks) {
        half8 af[4], wf[2];
#pragma unroll
        for (int i = 0; i < 4; ++i)
            af[i] = *((const half8*)&ldsA[(i * 16 + l16) * LDH + ks * 32 + quad * 8]);
#pragma unroll
        for (int j = 0; j < 2; ++j)
            wf[j] = *((const half8*)(w2t + ((ct0 + j) * 16 + l16) * 128 + ks * 32 + quad * 8));
#pragma unroll
        for (int i = 0; i < 4; ++i)
#pragma unroll
            for (int j = 0; j < 2; ++j)
                acc[i][j] = __builtin_amdgcn_mfma_f32_16x16x32_f16(wf[j], af[i], acc[i][j], 0, 0, 0);
    }
    __syncthreads();
#pragma unroll
    for (int j = 0; j < 2; ++j) {
        int c = ct0 + j;
        float4 bb = *((const float4*)&ldsB[128 + c * 16 + quad * 4]);
#pragma unroll
        for (int i = 0; i < 4; ++i) {
            float v0 = acc[i][j][0] + bb.x; v0 = v0 > 0.f ? v0 : 0.f;
            float v1 = acc[i][j][1] + bb.y; v1 = v1 > 0.f ? v1 : 0.f;
            float v2 = acc[i][j][2] + bb.z; v2 = v2 > 0.f ? v2 : 0.f;
            float v3 = acc[i][j][3] + bb.w; v3 = v3 > 0.f ? v3 : 0.f;
            __half2 h0 = __floats2half2_rn(v0, v1);
            __half2 h1 = __floats2half2_rn(v2, v3);
            uint2 o;
            o.x = __builtin_bit_cast(unsigned, h0);
            o.y = __builtin_bit_cast(unsigned, h1);
            *((uint2*)&ldsA[(i * 16 + l16) * LDH + c * 16 + quad * 4]) = o;
        }
    }
    __syncthreads();
    for (int i = t; i < 1024; i += 256) {
        int r = i >> 4, c = i & 15;
        int gr = br + r;
        if (gr < N) {
            uint4 hv = *((const uint4*)&ldsA[r * LDH + c * 8]);
            float2 f0 = __half22float2(__builtin_bit_cast(__half2, hv.x));
            float2 f1 = __half22float2(__builtin_bit_cast(__half2, hv.y));
            float2 f2 = __half22float2(__builtin_bit_cast(__half2, hv.z));
            float2 f3 = __half22float2(__builtin_bit_cast(__half2, hv.w));
            unsigned lo = __builtin_amdgcn_cvt_pk_fp8_f32(f0.x, f0.y, 0u, false);
            lo = __builtin_amdgcn_cvt_pk_fp8_f32(f1.x, f1.y, lo, true);
            unsigned hi = __builtin_amdgcn_cvt_pk_fp8_f32(f2.x, f2.y, 0u, false);
            hi = __builtin_amdgcn_cvt_pk_fp8_f32(f3.x, f3.y, hi, true);
            uint2 o8 = make_uint2(lo, hi);
            *((uint2*)(outq + (size_t)gr * F + c * 8)) = o8;
        }
    }
}

// ---------------- mlp2 (MFMA): out = log_softmax(relu(A@w3+b3)@w4+b4) ----------------
// Same global-weight pattern; LDS 18.1 KB -> 8 blocks/CU.

__global__ __launch_bounds__(256) void mlp2_mfma_kernel(const __half* __restrict__ A,
        const __half* __restrict__ w3t, const float* __restrict__ b3,
        const __half* __restrict__ w4t, const float* __restrict__ b4,
        float* __restrict__ out, int N) {
    __shared__ __half ldsA[64 * LDH];
    __shared__ float ldsB[176];
    int t = threadIdx.x;
    int wave = t >> 6, lane = t & 63, quad = lane >> 4, l16 = lane & 15;
    int br = blockIdx.x * 64;
    if (t < 128) ldsB[t] = b3[t];
    else if (t < 176) ldsB[t] = (t - 128 < C) ? b4[t - 128] : 0.f;
    for (int i = t; i < 1024; i += 256) {
        int r = i >> 4, c = i & 15;
        int gr = br + r;
        uint4 v = make_uint4(0u, 0u, 0u, 0u);
        if (gr < N) v = *((const uint4*)(A + (size_t)gr * F + c * 8));
        *((uint4*)&ldsA[r * LDH + c * 8]) = v;
    }
    __syncthreads();

    int ct0 = wave * 2;
    float4v acc[4][2];
    float4v zero = {0.f, 0.f, 0.f, 0.f};
#pragma unroll
    for (int i = 0; i < 4; ++i)
#pragma unroll
        for (int j = 0; j < 2; ++j) acc[i][j] = zero;
#pragma unroll
    for (int ks = 0; ks < 4; ++ks) {
        half8 af[4], wf[2];
#pragma unroll
        for (int i = 0; i < 4; ++i)
            af[i] = *((const half8*)&ldsA[(i * 16 + l16) * LDH + ks * 32 + quad * 8]);
#pragma unroll
        for (int j = 0; j < 2; ++j)
            wf[j] = *((const half8*)(w3t + ((ct0 + j) * 16 + l16) * 128 + ks * 32 + quad * 8));
#pragma unroll
        for (int i = 0; i < 4; ++i)
#pragma unroll
            for (int j = 0; j < 2; ++j)
                acc[i][j] = __builtin_amdgcn_mfma_f32_16x16x32_f16(wf[j], af[i], acc[i][j], 0, 0, 0);
    }
    __syncthreads();
#pragma unroll
    for (int j = 0; j < 2; ++j) {
        int c = ct0 + j;
        float4 bb = *((const float4*)&ldsB[c * 16 + quad * 4]);
#pragma unroll
        for (int i = 0; i < 4; ++i) {
            float v0 = acc[i][j][0] + bb.x; v0 = v0 > 0.f ? v0 : 0.f;
            float v1 = acc[i][j][1] + bb.y; v1 = v1 > 0.f ? v1 : 0.f;
            float v2 = acc[i][j][2] + bb.z; v2 = v2 > 0.f ? v2 : 0.f;
            float v3 = acc[i][j][3] + bb.w; v3 = v3 > 0.f ? v3 : 0.f;
            __half2 h0 = __floats2half2_rn(v0, v1);
            __half2 h1 = __floats2half2_rn(v2, v3);
            uint2 o;
            o.x = __builtin_bit_cast(unsigned, h0);
            o.y = __builtin_bit_cast(unsigned, h1);
            *((uint2*)&ldsA[(i * 16 + l16) * LDH + c * 16 + quad * 4]) = o;
        }
    }
    __syncthreads();

    float4v acc4[3];
#pragma unroll
    for (int c = 0; c < 3; ++c) acc4[c] = zero;
#pragma unroll
    for (int ks = 0; ks < 4; ++ks) {
        half8 af = *((const half8*)&ldsA[(wave * 16 + l16) * LDH + ks * 32 + quad * 8]);
#pragma unroll
        for (int c = 0; c < 3; ++c) {
            half8 wf = *((const half8*)(w4t + (c * 16 + l16) * 128 + ks * 32 + quad * 8));
            acc4[c] = __builtin_amdgcn_mfma_f32_16x16x32_f16(wf, af, acc4[c], 0, 0, 0);
        }
    }
    float lv[3][4];
#pragma unroll
    for (int c = 0; c < 3; ++c) {
        float4 bb = *((const float4*)&ldsB[128 + c * 16 + quad * 4]);
        lv[c][0] = acc4[c][0] + bb.x;
        lv[c][1] = acc4[c][1] + bb.y;
        lv[c][2] = acc4[c][2] + bb.z;
        lv[c][3] = acc4[c][3] + bb.w;
    }
    bool tile2ok = (quad < 2);
    float m = -1e30f;
#pragma unroll
    for (int c = 0; c < 3; ++c) {
        if (c == 2 && !tile2ok) continue;
#pragma unroll
        for (int r = 0; r < 4; ++r) m = fmaxf(m, lv[c][r]);
    }
    m = fmaxf(m, __shfl_xor(m, 16));
    m = fmaxf(m, __shfl_xor(m, 32));
    float ssum = 0.f;
#pragma unroll
    for (int c = 0; c < 3; ++c) {
        if (c == 2 && !tile2ok) continue;
#pragma unroll
        for (int r = 0; r < 4; ++r) ssum += __expf(lv[c][r] - m);
    }
    ssum += __shfl_xor(ssum, 16);
    ssum += __shfl_xor(ssum, 32);
    float L = m + __logf(ssum);
    int node = br + wave * 16 + l16;
    if (node < N) {
#pragma unroll
        for (int c = 0; c < 3; ++c) {
            if (c == 2 && !tile2ok) continue;
            float4 o = make_float4(lv[c][0] - L, lv[c][1] - L, lv[c][2] - L, lv[c][3] - L);
            *((float4*)(out + (size_t)node * C + c * 16 + quad * 4)) = o;
        }
    }
}

// ---------------- launch ----------------

extern "C" void kernel_launch(void* const* d_in, const int* in_sizes, int n_in,
                              void* d_out, int out_size, void* d_ws, size_t ws_size,
                              hipStream_t stream) {
    const float* x    = (const float*)d_in[0];
    const int*   ei   = (const int*)d_in[1];
    const float* eps1 = (const float*)d_in[2];
    const float* w1   = (const float*)d_in[3];
    const float* b1   = (const float*)d_in[4];
    const float* w2   = (const float*)d_in[5];
    const float* b2   = (const float*)d_in[6];
    const float* eps2 = (const float*)d_in[7];
    const float* w3   = (const float*)d_in[8];
    const float* b3   = (const float*)d_in[9];
    const float* w4   = (const float*)d_in[10];
    const float* b4   = (const float*)d_in[11];
    float* out = (float*)d_out;

    int N = in_sizes[0] / F;       // 100000
    int E = in_sizes[1] / 2;       // 1600000
    const int* srcp = ei;
    const int* dstp = ei + E;

    int NB = (N + BSIZE - 1) >> BSHIFT;   // 391 coarse buckets (<= 512)
    int BA = (E + CHUNK - 1) / CHUNK;     // 391 hist/scatter blocks

    // workspace layout
    __half* h0_h = (__half*)d_ws;                   // N*F fp16 (agg out / mlp in)
    __half* w1t  = h0_h + (size_t)N * F;            // 128*128
    __half* w2t  = w1t + 128 * 128;
    __half* w3t  = w2t + 128 * 128;
    __half* w4t  = w3t + 128 * 128;                 // 48*128
    unsigned char* fq = (unsigned char*)(w4t + 48 * 128);  // (N+1)*128 fp8 (+dummy zero row)
    unsigned* pairs   = (unsigned*)(fq + (size_t)(N + 1) * F);  // E
    int* row_start    = (int*)(pairs + E);          // N+1
    unsigned* src_sorted = (unsigned*)(row_start + (N + 1));  // E + 32 (padded byte offsets)
    int* coarse_count = (int*)(src_sorted + E + 32);  // 512
    int* pos0         = coarse_count + 512;          // 512 (scatter cursors)

    int n4 = N * F / 4;
    int NCONV = (n4 + 255) / 256;

    // zero bucket counters + scatter cursors (contiguous), then fused prep
    hipMemsetAsync(coarse_count, 0, 1024 * sizeof(int), stream);
    fused_prep_kernel<<<BA + 4 + NCONV, 256, 0, stream>>>(x, fq, n4, dstp, E, NB,
                                                          coarse_count, w1, w2, w3, w4,
                                                          w1t, w2t, w3t, w4t, BA, N);

    // CSR build: scan-fused bucket scatter -> per-bucket LDS sort
    bucket_scatter_kernel<<<BA, 512, 0, stream>>>(srcp, dstp, E, NB, coarse_count, pos0, pairs);
    bucket_sort_kernel<<<NB, 512, 0, stream>>>(pairs, coarse_count, NB, N, E, row_start,
                                               src_sorted);

    // layer 1: gather+self fp8 x -> h0 fp16; mlp1 emits fp8 h (reuses fq)
    agg_f16_kernel<<<(N + 3) / 4, 256, 0, stream>>>(fq, row_start, src_sorted, eps1, h0_h, N);
    mlp1_mfma_kernel<<<(N + 63) / 64, 256, 0, stream>>>(h0_h, w1t, b1, w2t, b2, fq, N);
    // layer 2
    agg_f16_kernel<<<(N + 3) / 4, 256, 0, stream>>>(fq, row_start, src_sorted, eps2, h0_h, N);
    mlp2_mfma_kernel<<<(N + 63) / 64, 256, 0, stream>>>(h0_h, w3t, b3, w4t, b4, out, N);
}

// Round 14
// 286.924 us; speedup vs baseline: 1.0400x; 1.0400x over previous
//
#include <hip/hip_runtime.h>
#include <hip/hip_fp16.h>
#include <math.h>

constexpr int F = 128;
constexpr int C = 40;
constexpr int LDH = 136;   // padded LDS stride in halves
constexpr int BSHIFT = 8;  // 256 dst per coarse bucket
constexpr int BSIZE = 1 << BSHIFT;
constexpr int CHUNK = 4096;  // edges per histogram/scatter block (391 blocks)

typedef __attribute__((ext_vector_type(8))) _Float16 half8;
typedef __attribute__((ext_vector_type(4))) float float4v;
typedef __attribute__((ext_vector_type(2))) float floatx2;

// ---------------- fused prep: conv fp32->fp8 + weight transpose + coarse hist ----------------
// blocks [0,BA): coarse histogram; [BA,BA+4): weight transpose (16KB staging, 4 passes) —
// the w4 block also zeroes fp8 row N (dummy row for agg address-masking);
// rest: x fp32 -> fp8 e4m3 row-major (the ONLY feature table — self term also decoded fp8).
// coarse_count+pos0 pre-zeroed by hipMemsetAsync.

__global__ __launch_bounds__(256) void fused_prep_kernel(
        const float* __restrict__ x, unsigned char* __restrict__ xq, int n4,
        const int* __restrict__ dst, int E, int NB, int* __restrict__ coarse_count,
        const float* __restrict__ w1, const float* __restrict__ w2,
        const float* __restrict__ w3, const float* __restrict__ w4,
        __half* __restrict__ w1t, __half* __restrict__ w2t,
        __half* __restrict__ w3t, __half* __restrict__ w4t, int BA, int N) {
    __shared__ float smem[4096];  // 16KB, shared by all roles
    int b = blockIdx.x, t = threadIdx.x;
    if (b < BA) {
        int* hist = (int*)smem;
        int c0 = b * CHUNK, cend = min(c0 + CHUNK, E);
        for (int i = t; i < NB; i += 256) hist[i] = 0;
        __syncthreads();
        for (int i = c0 + t; i < cend; i += 256)
            atomicAdd(&hist[dst[i] >> BSHIFT], 1);
        __syncthreads();
        for (int i = t; i < NB; i += 256)
            if (hist[i]) atomicAdd(&coarse_count[i], hist[i]);
        return;
    }
    if (b < BA + 4) {
        const float* in; __half* outp; int Nin, Npad;
        switch (b - BA) {
            case 0:  in = w1; outp = w1t; Nin = 128; Npad = 128; break;
            case 1:  in = w2; outp = w2t; Nin = 128; Npad = 128; break;
            case 2:  in = w3; outp = w3t; Nin = 128; Npad = 128; break;
            default: in = w4; outp = w4t; Nin = 40;  Npad = 48;  break;
        }
        for (int p = 0; p < 4; ++p) {  // k rows [32p, 32p+32)
            int nf4 = 32 * Nin / 4;
            const float4* srcv = (const float4*)(in + 32 * p * Nin);
            for (int i = t; i < nf4; i += 256) ((float4*)smem)[i] = srcv[i];
            __syncthreads();
            int total = Npad * 16;
            for (int i = t; i < total; i += 256) {
                int n = i >> 4, wl = i & 15;
                float lo = 0.f, hi = 0.f;
                if (n < Nin) {
                    lo = smem[(2 * wl) * Nin + n];
                    hi = smem[(2 * wl + 1) * Nin + n];
                }
                __half2 h = __floats2half2_rn(lo, hi);
                ((unsigned*)outp)[n * 64 + 16 * p + wl] = __builtin_bit_cast(unsigned, h);
            }
            __syncthreads();
        }
        if (b - BA == 3 && t < 8)  // zero dummy row fq[N] (survives mlp1: it writes rows < N)
            *(((uint4*)(xq + (size_t)N * F)) + t) = make_uint4(0u, 0u, 0u, 0u);
        return;
    }
    int i = (b - BA - 4) * 256 + t;
    if (i >= n4) return;
    float4 v = ((const float4*)x)[i];
    unsigned p8 = __builtin_amdgcn_cvt_pk_fp8_f32(v.x, v.y, 0u, false);
    p8 = __builtin_amdgcn_cvt_pk_fp8_f32(v.z, v.w, p8, true);
    ((unsigned*)xq)[i] = p8;
}

// ---------------- CSR build: scan-fused scatter + per-bucket sort (r9-proven) ----------------
// Both kernels redundantly compute the <=512-entry exclusive scan of coarse_count in LDS
// (deterministic); scatter allocates cursors via memset-zeroed pos0[].

__global__ __launch_bounds__(512) void bucket_scatter_kernel(
        const int* __restrict__ src, const int* __restrict__ dst, int E, int NB,
        const int* __restrict__ coarse_count, int* __restrict__ pos0,
        unsigned* __restrict__ pairs) {
    __shared__ int scn[512];
    __shared__ int hist[512];
    __shared__ int base[512];
    int t = threadIdx.x;
    int v = (t < NB) ? coarse_count[t] : 0;
    scn[t] = v;
    __syncthreads();
    for (int d = 1; d < 512; d <<= 1) {
        int add = (t >= d) ? scn[t - d] : 0;
        __syncthreads();
        scn[t] += add;
        __syncthreads();
    }
    int cstart = scn[t] - v;  // exclusive prefix for bucket t
    hist[t] = 0;
    __syncthreads();
    int c0 = blockIdx.x * CHUNK, cend = min(c0 + CHUNK, E);
    for (int i = c0 + t; i < cend; i += 512)
        atomicAdd(&hist[dst[i] >> BSHIFT], 1);
    __syncthreads();
    int h = hist[t];
    base[t] = (h > 0) ? (cstart + atomicAdd(&pos0[t], h)) : 0;
    hist[t] = 0;  // reuse as local offset
    __syncthreads();
    for (int i = c0 + t; i < cend; i += 512) {
        int d = dst[i];
        int b = d >> BSHIFT;
        int p = base[b] + atomicAdd(&hist[b], 1);
        pairs[p] = ((unsigned)(d & (BSIZE - 1)) << 24) | (unsigned)src[i];
    }
}

// one block per bucket; redundant coarse scan -> fine hist + scan -> row_start + PRE-SHIFTED
// byte-offset scatter (src*128). Last block pads src_sorted[E..E+31] with the dummy offset.
__global__ __launch_bounds__(512) void bucket_sort_kernel(const unsigned* __restrict__ pairs,
                                                          const int* __restrict__ coarse_count,
                                                          int NB, int N, int E,
                                                          int* __restrict__ row_start,
                                                          unsigned* __restrict__ src_sorted) {
    __shared__ int scn[512];
    __shared__ int hist[256];
    __shared__ int tmp[256];
    int b = blockIdx.x, t = threadIdx.x;
    int v = (t < NB) ? coarse_count[t] : 0;
    scn[t] = v;
    __syncthreads();
    for (int d = 1; d < 512; d <<= 1) {
        int add = (t >= d) ? scn[t - d] : 0;
        __syncthreads();
        scn[t] += add;
        __syncthreads();
    }
    int end = scn[b];
    int start = end - coarse_count[b];
    int base = b << BSHIFT;
    if (t < 256) hist[t] = 0;
    __syncthreads();
    for (int i = start + t; i < end; i += 512)
        atomicAdd(&hist[pairs[i] >> 24], 1);
    __syncthreads();
    int hv = (t < 256) ? hist[t] : 0;
    if (t < 256) tmp[t] = hv;
    __syncthreads();
    for (int d = 1; d < 256; d <<= 1) {
        int add = (t >= d && t < 256) ? tmp[t - d] : 0;
        __syncthreads();
        if (t < 256) tmp[t] += add;
        __syncthreads();
    }
    if (t < 256) {
        int ex = start + tmp[t] - hv;
        if (base + t < N) row_start[base + t] = ex;
        hist[t] = ex;
    }
    __syncthreads();
    for (int i = start + t; i < end; i += 512) {
        unsigned u = pairs[i];
        int p = atomicAdd(&hist[u >> 24], 1);
        src_sorted[p] = (u & 0x00FFFFFFu) << 7;   // byte offset (row stride 128)
    }
    if (b == NB - 1 && t < 32) src_sorted[E + t] = ((unsigned)N) << 7;
    if (b == 0 && t == 0) row_start[N] = E;
}

// ---------------- aggregation: fp8 gather + fp8 self, byte-offset CSR, dummy-row masking ----
// r1/r6-proven structure: one wave per node, 16-edge batches, 4 independent row gathers in
// flight (uint2/lane fp8 rows). src_sorted holds PRE-SHIFTED byte offsets (padded past E);
// invalid slots redirect to the zero row fq[N]. Decode via v_cvt_pk_f32_fp8, packed-f32
// accumulate; self term ALSO decoded from the fp8 table (no fp16 copy exists).

__global__ __launch_bounds__(256) void agg_f16_kernel(const unsigned char* __restrict__ featq,
        const int* __restrict__ row_start, const unsigned* __restrict__ src_sorted,
        const float* __restrict__ eps_ptr, __half* __restrict__ out, int N) {
    int wid = (int)((blockIdx.x * blockDim.x + threadIdx.x) >> 6);
    int lane = threadIdx.x & 63;
    if (wid >= N) return;
    int q = lane >> 4, l16 = lane & 15;
    int s = row_start[wid], e = row_start[wid + 1];
    const unsigned dummy = ((unsigned)N) << 7;
    const unsigned char* fb = featq + l16 * 8;  // per-lane base (folds the l16*8)
    uint2 su = *((const uint2*)(fb + ((size_t)(unsigned)wid << 7)));  // self (issued early)
    float ep1 = 1.0f + *eps_ptr;
    floatx2 accA[4], accB[4];
#pragma unroll
    for (int j = 0; j < 4; ++j) {
        accA[j] = (floatx2){0.f, 0.f};
        accB[j] = (floatx2){0.f, 0.f};
    }
    for (int i0 = s; i0 < e; i0 += 16) {
        unsigned off = src_sorted[i0 + l16];  // padded region makes this always safe
        unsigned o0 = (unsigned)__shfl((int)off, q);
        unsigned o1 = (unsigned)__shfl((int)off, q + 4);
        unsigned o2 = (unsigned)__shfl((int)off, q + 8);
        unsigned o3 = (unsigned)__shfl((int)off, q + 12);
        o0 = (i0 + q < e) ? o0 : dummy;
        o1 = (i0 + q + 4 < e) ? o1 : dummy;
        o2 = (i0 + q + 8 < e) ? o2 : dummy;
        o3 = (i0 + q + 12 < e) ? o3 : dummy;
        uint2 u0 = *((const uint2*)(fb + o0));
        uint2 u1 = *((const uint2*)(fb + o1));
        uint2 u2 = *((const uint2*)(fb + o2));
        uint2 u3 = *((const uint2*)(fb + o3));
        accA[0] += __builtin_amdgcn_cvt_pk_f32_fp8(u0.x, false);
        accA[1] += __builtin_amdgcn_cvt_pk_f32_fp8(u0.x, true);
        accA[2] += __builtin_amdgcn_cvt_pk_f32_fp8(u0.y, false);
        accA[3] += __builtin_amdgcn_cvt_pk_f32_fp8(u0.y, true);
        accB[0] += __builtin_amdgcn_cvt_pk_f32_fp8(u1.x, false);
        accB[1] += __builtin_amdgcn_cvt_pk_f32_fp8(u1.x, true);
        accB[2] += __builtin_amdgcn_cvt_pk_f32_fp8(u1.y, false);
        accB[3] += __builtin_amdgcn_cvt_pk_f32_fp8(u1.y, true);
        accA[0] += __builtin_amdgcn_cvt_pk_f32_fp8(u2.x, false);
        accA[1] += __builtin_amdgcn_cvt_pk_f32_fp8(u2.x, true);
        accA[2] += __builtin_amdgcn_cvt_pk_f32_fp8(u2.y, false);
        accA[3] += __builtin_amdgcn_cvt_pk_f32_fp8(u2.y, true);
        accB[0] += __builtin_amdgcn_cvt_pk_f32_fp8(u3.x, false);
        accB[1] += __builtin_amdgcn_cvt_pk_f32_fp8(u3.x, true);
        accB[2] += __builtin_amdgcn_cvt_pk_f32_fp8(u3.y, false);
        accB[3] += __builtin_amdgcn_cvt_pk_f32_fp8(u3.y, true);
    }
    float a[8];
#pragma unroll
    for (int j = 0; j < 4; ++j) {
        floatx2 m = accA[j] + accB[j];
        a[2 * j] = m.x;
        a[2 * j + 1] = m.y;
    }
#pragma unroll
    for (int j = 0; j < 8; ++j) {
        a[j] += __shfl_xor(a[j], 16);
        a[j] += __shfl_xor(a[j], 32);
    }
    if (q == 0) {
        floatx2 s01 = __builtin_amdgcn_cvt_pk_f32_fp8(su.x, false);
        floatx2 s23 = __builtin_amdgcn_cvt_pk_f32_fp8(su.x, true);
        floatx2 s45 = __builtin_amdgcn_cvt_pk_f32_fp8(su.y, false);
        floatx2 s67 = __builtin_amdgcn_cvt_pk_f32_fp8(su.y, true);
        a[0] = fmaf(ep1, s01.x, a[0]); a[1] = fmaf(ep1, s01.y, a[1]);
        a[2] = fmaf(ep1, s23.x, a[2]); a[3] = fmaf(ep1, s23.y, a[3]);
        a[4] = fmaf(ep1, s45.x, a[4]); a[5] = fmaf(ep1, s45.y, a[5]);
        a[6] = fmaf(ep1, s67.x, a[6]); a[7] = fmaf(ep1, s67.y, a[7]);
        uint4 ou;
        ou.x = __builtin_bit_cast(unsigned, __floats2half2_rn(a[0], a[1]));
        ou.y = __builtin_bit_cast(unsigned, __floats2half2_rn(a[2], a[3]));
        ou.z = __builtin_bit_cast(unsigned, __floats2half2_rn(a[4], a[5]));
        ou.w = __builtin_bit_cast(unsigned, __floats2half2_rn(a[6], a[7]));
        *(((uint4*)(out + (size_t)wid * F)) + l16) = ou;
    }
}

// ---------------- mlp1 (MFMA): fq = fp8(relu(relu(A@w1+b1)@w2+b2)) — fp8 out ONLY ----------

__global__ __launch_bounds__(256) void mlp1_mfma_kernel(const __half* __restrict__ A,
        const __half* __restrict__ w1t, const float* __restrict__ b1,
        const __half* __restrict__ w2t, const float* __restrict__ b2,
        unsigned char* __restrict__ outq, int N) {
    __shared__ __half ldsA[64 * LDH];
    __shared__ __half ldsW[128 * LDH];
    __shared__ float ldsB[256];
    int t = threadIdx.x;
    int wave = t >> 6, lane = t & 63, quad = lane >> 4, l16 = lane & 15;
    int br = blockIdx.x * 64;
    if (t < 128) ldsB[t] = b1[t];
    else         ldsB[t] = b2[t - 128];
    for (int i = t; i < 1024; i += 256) {
        int r = i >> 4, c = i & 15;
        int gr = br + r;
        uint4 v = make_uint4(0u, 0u, 0u, 0u);
        if (gr < N) v = *((const uint4*)(A + (size_t)gr * F + c * 8));
        *((uint4*)&ldsA[r * LDH + c * 8]) = v;
    }
    for (int i = t; i < 2048; i += 256) {
        int r = i >> 4, c = i & 15;
        *((uint4*)&ldsW[r * LDH + c * 8]) = *((const uint4*)(w1t + r * 128 + c * 8));
    }
    __syncthreads();

    int ct0 = wave * 2;
    float4v acc[4][2];
    float4v zero = {0.f, 0.f, 0.f, 0.f};
#pragma unroll
    for (int i = 0; i < 4; ++i)
#pragma unroll
        for (int j = 0; j < 2; ++j) acc[i][j] = zero;

#pragma unroll
    for (int ks = 0; ks < 4; ++ks) {
        half8 af[4], wf[2];
#pragma unroll
        for (int i = 0; i < 4; ++i)
            af[i] = *((const half8*)&ldsA[(i * 16 + l16) * LDH + ks * 32 + quad * 8]);
#pragma unroll
        for (int j = 0; j < 2; ++j)
            wf[j] = *((const half8*)&ldsW[((ct0 + j) * 16 + l16) * LDH + ks * 32 + quad * 8]);
#pragma unroll
        for (int i = 0; i < 4; ++i)
#pragma unroll
            for (int j = 0; j < 2; ++j)
                acc[i][j] = __builtin_amdgcn_mfma_f32_16x16x32_f16(wf[j], af[i], acc[i][j], 0, 0, 0);
    }
    __syncthreads();
#pragma unroll
    for (int j = 0; j < 2; ++j) {
        int c = ct0 + j;
        float4 bb = *((const float4*)&ldsB[c * 16 + quad * 4]);
#pragma unroll
        for (int i = 0; i < 4; ++i) {
            float v0 = acc[i][j][0] + bb.x; v0 = v0 > 0.f ? v0 : 0.f;
            float v1 = acc[i][j][1] + bb.y; v1 = v1 > 0.f ? v1 : 0.f;
            float v2 = acc[i][j][2] + bb.z; v2 = v2 > 0.f ? v2 : 0.f;
            float v3 = acc[i][j][3] + bb.w; v3 = v3 > 0.f ? v3 : 0.f;
            __half2 h0 = __floats2half2_rn(v0, v1);
            __half2 h1 = __floats2half2_rn(v2, v3);
            uint2 o;
            o.x = __builtin_bit_cast(unsigned, h0);
            o.y = __builtin_bit_cast(unsigned, h1);
            *((uint2*)&ldsA[(i * 16 + l16) * LDH + c * 16 + quad * 4]) = o;
        }
    }
    for (int i = t; i < 2048; i += 256) {
        int r = i >> 4, c = i & 15;
        *((uint4*)&ldsW[r * LDH + c * 8]) = *((const uint4*)(w2t + r * 128 + c * 8));
    }
    __syncthreads();

#pragma unroll
    for (int i = 0; i < 4; ++i)
#pragma unroll
        for (int j = 0; j < 2; ++j) acc[i][j] = zero;
#pragma unroll
    for (int ks = 0; ks < 4; ++ks) {
        half8 af[4], wf[2];
#pragma unroll
        for (int i = 0; i < 4; ++i)
            af[i] = *((const half8*)&ldsA[(i * 16 + l16) * LDH + ks * 32 + quad * 8]);
#pragma unroll
        for (int j = 0; j < 2; ++j)
            wf[j] = *((const half8*)&ldsW[((ct0 + j) * 16 + l16) * LDH + ks * 32 + quad * 8]);
#pragma unroll
        for (int i = 0; i < 4; ++i)
#pragma unroll
            for (int j = 0; j < 2; ++j)
                acc[i][j] = __builtin_amdgcn_mfma_f32_16x16x32_f16(wf[j], af[i], acc[i][j], 0, 0, 0);
    }
    __syncthreads();
#pragma unroll
    for (int j = 0; j < 2; ++j) {
        int c = ct0 + j;
        float4 bb = *((const float4*)&ldsB[128 + c * 16 + quad * 4]);
#pragma unroll
        for (int i = 0; i < 4; ++i) {
            float v0 = acc[i][j][0] + bb.x; v0 = v0 > 0.f ? v0 : 0.f;
            float v1 = acc[i][j][1] + bb.y; v1 = v1 > 0.f ? v1 : 0.f;
            float v2 = acc[i][j][2] + bb.z; v2 = v2 > 0.f ? v2 : 0.f;
            float v3 = acc[i][j][3] + bb.w; v3 = v3 > 0.f ? v3 : 0.f;
            __half2 h0 = __floats2half2_rn(v0, v1);
            __half2 h1 = __floats2half2_rn(v2, v3);
            uint2 o;
            o.x = __builtin_bit_cast(unsigned, h0);
            o.y = __builtin_bit_cast(unsigned, h1);
            *((uint2*)&ldsA[(i * 16 + l16) * LDH + c * 16 + quad * 4]) = o;
        }
    }
    __syncthreads();
    for (int i = t; i < 1024; i += 256) {
        int r = i >> 4, c = i & 15;
        int gr = br + r;
        if (gr < N) {
            uint4 hv = *((const uint4*)&ldsA[r * LDH + c * 8]);
            float2 f0 = __half22float2(__builtin_bit_cast(__half2, hv.x));
            float2 f1 = __half22float2(__builtin_bit_cast(__half2, hv.y));
            float2 f2 = __half22float2(__builtin_bit_cast(__half2, hv.z));
            float2 f3 = __half22float2(__builtin_bit_cast(__half2, hv.w));
            unsigned lo = __builtin_amdgcn_cvt_pk_fp8_f32(f0.x, f0.y, 0u, false);
            lo = __builtin_amdgcn_cvt_pk_fp8_f32(f1.x, f1.y, lo, true);
            unsigned hi = __builtin_amdgcn_cvt_pk_fp8_f32(f2.x, f2.y, 0u, false);
            hi = __builtin_amdgcn_cvt_pk_fp8_f32(f3.x, f3.y, hi, true);
            uint2 o8 = make_uint2(lo, hi);
            *((uint2*)(outq + (size_t)gr * F + c * 8)) = o8;
        }
    }
}

// ---------------- mlp2 (MFMA): out = log_softmax(relu(A@w3+b3)@w4+b4) ----------------

__global__ __launch_bounds__(256) void mlp2_mfma_kernel(const __half* __restrict__ A,
        const __half* __restrict__ w3t, const float* __restrict__ b3,
        const __half* __restrict__ w4t, const float* __restrict__ b4,
        float* __restrict__ out, int N) {
    __shared__ __half ldsA[64 * LDH];
    __shared__ __half ldsW[128 * LDH];
    __shared__ float ldsB[176];
    int t = threadIdx.x;
    int wave = t >> 6, lane = t & 63, quad = lane >> 4, l16 = lane & 15;
    int br = blockIdx.x * 64;
    if (t < 128) ldsB[t] = b3[t];
    else if (t < 176) ldsB[t] = (t - 128 < C) ? b4[t - 128] : 0.f;
    for (int i = t; i < 1024; i += 256) {
        int r = i >> 4, c = i & 15;
        int gr = br + r;
        uint4 v = make_uint4(0u, 0u, 0u, 0u);
        if (gr < N) v = *((const uint4*)(A + (size_t)gr * F + c * 8));
        *((uint4*)&ldsA[r * LDH + c * 8]) = v;
    }
    for (int i = t; i < 2048; i += 256) {
        int r = i >> 4, c = i & 15;
        *((uint4*)&ldsW[r * LDH + c * 8]) = *((const uint4*)(w3t + r * 128 + c * 8));
    }
    __syncthreads();

    int ct0 = wave * 2;
    float4v acc[4][2];
    float4v zero = {0.f, 0.f, 0.f, 0.f};
#pragma unroll
    for (int i = 0; i < 4; ++i)
#pragma unroll
        for (int j = 0; j < 2; ++j) acc[i][j] = zero;
#pragma unroll
    for (int ks = 0; ks < 4; ++ks) {
        half8 af[4], wf[2];
#pragma unroll
        for (int i = 0; i < 4; ++i)
            af[i] = *((const half8*)&ldsA[(i * 16 + l16) * LDH + ks * 32 + quad * 8]);
#pragma unroll
        for (int j = 0; j < 2; ++j)
            wf[j] = *((const half8*)&ldsW[((ct0 + j) * 16 + l16) * LDH + ks * 32 + quad * 8]);
#pragma unroll
        for (int i = 0; i < 4; ++i)
#pragma unroll
            for (int j = 0; j < 2; ++j)
                acc[i][j] = __builtin_amdgcn_mfma_f32_16x16x32_f16(wf[j], af[i], acc[i][j], 0, 0, 0);
    }
    __syncthreads();
#pragma unroll
    for (int j = 0; j < 2; ++j) {
        int c = ct0 + j;
        float4 bb = *((const float4*)&ldsB[c * 16 + quad * 4]);
#pragma unroll
        for (int i = 0; i < 4; ++i) {
            float v0 = acc[i][j][0] + bb.x; v0 = v0 > 0.f ? v0 : 0.f;
            float v1 = acc[i][j][1] + bb.y; v1 = v1 > 0.f ? v1 : 0.f;
            float v2 = acc[i][j][2] + bb.z; v2 = v2 > 0.f ? v2 : 0.f;
            float v3 = acc[i][j][3] + bb.w; v3 = v3 > 0.f ? v3 : 0.f;
            __half2 h0 = __floats2half2_rn(v0, v1);
            __half2 h1 = __floats2half2_rn(v2, v3);
            uint2 o;
            o.x = __builtin_bit_cast(unsigned, h0);
            o.y = __builtin_bit_cast(unsigned, h1);
            *((uint2*)&ldsA[(i * 16 + l16) * LDH + c * 16 + quad * 4]) = o;
        }
    }
    for (int i = t; i < 768; i += 256) {
        int r = i >> 4, c = i & 15;
        *((uint4*)&ldsW[r * LDH + c * 8]) = *((const uint4*)(w4t + r * 128 + c * 8));
    }
    __syncthreads();

    float4v acc4[3];
#pragma unroll
    for (int c = 0; c < 3; ++c) acc4[c] = zero;
#pragma unroll
    for (int ks = 0; ks < 4; ++ks) {
        half8 af = *((const half8*)&ldsA[(wave * 16 + l16) * LDH + ks * 32 + quad * 8]);
#pragma unroll
        for (int c = 0; c < 3; ++c) {
            half8 wf = *((const half8*)&ldsW[(c * 16 + l16) * LDH + ks * 32 + quad * 8]);
            acc4[c] = __builtin_amdgcn_mfma_f32_16x16x32_f16(wf, af, acc4[c], 0, 0, 0);
        }
    }
    float lv[3][4];
#pragma unroll
    for (int c = 0; c < 3; ++c) {
        float4 bb = *((const float4*)&ldsB[128 + c * 16 + quad * 4]);
        lv[c][0] = acc4[c][0] + bb.x;
        lv[c][1] = acc4[c][1] + bb.y;
        lv[c][2] = acc4[c][2] + bb.z;
        lv[c][3] = acc4[c][3] + bb.w;
    }
    bool tile2ok = (quad < 2);
    float m = -1e30f;
#pragma unroll
    for (int c = 0; c < 3; ++c) {
        if (c == 2 && !tile2ok) continue;
#pragma unroll
        for (int r = 0; r < 4; ++r) m = fmaxf(m, lv[c][r]);
    }
    m = fmaxf(m, __shfl_xor(m, 16));
    m = fmaxf(m, __shfl_xor(m, 32));
    float ssum = 0.f;
#pragma unroll
    for (int c = 0; c < 3; ++c) {
        if (c == 2 && !tile2ok) continue;
#pragma unroll
        for (int r = 0; r < 4; ++r) ssum += __expf(lv[c][r] - m);
    }
    ssum += __shfl_xor(ssum, 16);
    ssum += __shfl_xor(ssum, 32);
    float L = m + __logf(ssum);
    int node = br + wave * 16 + l16;
    if (node < N) {
#pragma unroll
        for (int c = 0; c < 3; ++c) {
            if (c == 2 && !tile2ok) continue;
            float4 o = make_float4(lv[c][0] - L, lv[c][1] - L, lv[c][2] - L, lv[c][3] - L);
            *((float4*)(out + (size_t)node * C + c * 16 + quad * 4)) = o;
        }
    }
}

// ---------------- launch ----------------

extern "C" void kernel_launch(void* const* d_in, const int* in_sizes, int n_in,
                              void* d_out, int out_size, void* d_ws, size_t ws_size,
                              hipStream_t stream) {
    const float* x    = (const float*)d_in[0];
    const int*   ei   = (const int*)d_in[1];
    const float* eps1 = (const float*)d_in[2];
    const float* w1   = (const float*)d_in[3];
    const float* b1   = (const float*)d_in[4];
    const float* w2   = (const float*)d_in[5];
    const float* b2   = (const float*)d_in[6];
    const float* eps2 = (const float*)d_in[7];
    const float* w3   = (const float*)d_in[8];
    const float* b3   = (const float*)d_in[9];
    const float* w4   = (const float*)d_in[10];
    const float* b4   = (const float*)d_in[11];
    float* out = (float*)d_out;

    int N = in_sizes[0] / F;       // 100000
    int E = in_sizes[1] / 2;       // 1600000
    const int* srcp = ei;
    const int* dstp = ei + E;

    int NB = (N + BSIZE - 1) >> BSHIFT;   // 391 coarse buckets (<= 512)
    int BA = (E + CHUNK - 1) / CHUNK;     // 391 hist/scatter blocks

    // workspace layout
    __half* h0_h = (__half*)d_ws;                   // N*F fp16 (agg out / mlp in)
    __half* w1t  = h0_h + (size_t)N * F;            // 128*128
    __half* w2t  = w1t + 128 * 128;
    __half* w3t  = w2t + 128 * 128;
    __half* w4t  = w3t + 128 * 128;                 // 48*128
    unsigned char* fq = (unsigned char*)(w4t + 48 * 128);  // (N+1)*128 fp8 (+dummy zero row)
    unsigned* pairs   = (unsigned*)(fq + (size_t)(N + 1) * F);  // E
    int* row_start    = (int*)(pairs + E);          // N+1
    unsigned* src_sorted = (unsigned*)(row_start + (N + 1));  // E + 32 (padded byte offsets)
    int* coarse_count = (int*)(src_sorted + E + 32);  // 512
    int* pos0         = coarse_count + 512;          // 512 (scatter cursors)

    int n4 = N * F / 4;
    int NCONV = (n4 + 255) / 256;

    // zero bucket counters + scatter cursors (contiguous), then fused prep
    hipMemsetAsync(coarse_count, 0, 1024 * sizeof(int), stream);
    fused_prep_kernel<<<BA + 4 + NCONV, 256, 0, stream>>>(x, fq, n4, dstp, E, NB,
                                                          coarse_count, w1, w2, w3, w4,
                                                          w1t, w2t, w3t, w4t, BA, N);

    // CSR build: scan-fused bucket scatter -> per-bucket LDS sort
    bucket_scatter_kernel<<<BA, 512, 0, stream>>>(srcp, dstp, E, NB, coarse_count, pos0, pairs);
    bucket_sort_kernel<<<NB, 512, 0, stream>>>(pairs, coarse_count, NB, N, E, row_start,
                                               src_sorted);

    // layer 1: gather+self fp8 x -> h0 fp16; mlp1 emits fp8 h (reuses fq)
    agg_f16_kernel<<<(N + 3) / 4, 256, 0, stream>>>(fq, row_start, src_sorted, eps1, h0_h, N);
    mlp1_mfma_kernel<<<(N + 63) / 64, 256, 0, stream>>>(h0_h, w1t, b1, w2t, b2, fq, N);
    // layer 2
    agg_f16_kernel<<<(N + 3) / 4, 256, 0, stream>>>(fq, row_start, src_sorted, eps2, h0_h, N);
    mlp2_mfma_kernel<<<(N + 63) / 64, 256, 0, stream>>>(h0_h, w3t, b3, w4t, b4, out, N);
}